// Round 1
// baseline (1080.062 us; speedup 1.0000x reference)
//
#include <hip/hip_runtime.h>
#include <hip/hip_bf16.h>
#include <stdint.h>

typedef unsigned short u16;
typedef unsigned int u32;

#define BT 256
#define NPIX 4096
#define HID 1024
#define NC 98304          // NPIX*3*K_BINS
#define TB 8.0f

typedef __attribute__((ext_vector_type(8))) short short8;   // 8 bf16 (4 VGPR)
typedef __attribute__((ext_vector_type(4))) float f32x4;

typedef __attribute__((address_space(1))) void as1_void;
typedef __attribute__((address_space(3))) void as3_void;

__device__ __forceinline__ u16 f2bf(float f) {
  union { __hip_bfloat16 b; u16 u; } cv;
  cv.b = __float2bfloat16(f);   // RNE
  return cv.u;
}

__device__ __forceinline__ void glds16(const void* g, void* l) {
  // width=16 direct global->LDS (m97 pattern); dest is wave-uniform + lane*16
  __builtin_amdgcn_global_load_lds((as1_void*)g, (as3_void*)l, 16, 0, 0);
}

// ---------------------------------------------------------------- prep ------
__global__ __launch_bounds__(256) void k_prep(float* hpre, float* ldacc,
                                              float* maskf, const int* mask) {
  const int i = blockIdx.x * 256 + threadIdx.x;           // grid 2048 -> 524288
  if (i < 2 * BT * HID) hpre[i] = 0.f;                    // both split-K buffers
  if (i < BT * 64) ldacc[i] = 0.f;
  if (i < NPIX) maskf[i] = (float)mask[i];
}

// -------------------------------------------------------------- gemm1 ------
// h_pre += (x[*mask]) @ w1 ; split-K over grid.z, f32 atomics.
// Tile: M=64, N=64, Kc=32. A planes [4u][64r][8] bf16; B_T [64n][40k-pad] bf16.
__global__ __launch_bounds__(256) void k_gemm1(
    const float* __restrict__ src, const float* __restrict__ maskf,
    const float* __restrict__ w1, float* __restrict__ hpre, const int use_mask) {
  __shared__ __align__(16) u16 Apl[4 * 64 * 8];
  __shared__ __align__(16) u16 Bt[64 * 40];

  const int tid = threadIdx.x;
  const int lane = tid & 63;
  const int wv = tid >> 6;
  const int n0 = blockIdx.x * 64;
  const int m0 = blockIdx.y * 64;
  const int kbase = blockIdx.z * 512;

  f32x4 acc[4];
#pragma unroll
  for (int i = 0; i < 4; ++i) acc[i] = f32x4{0.f, 0.f, 0.f, 0.f};

  const int arow = tid >> 2, au = tid & 3;     // A stage: row, 16B unit
  const int bp = tid >> 4, bf4 = tid & 15;     // B stage: k-pair, float4 col

  for (int kc = 0; kc < 16; ++kc) {
    const int k0 = kbase + kc * 32;
    __syncthreads();
    { // A: 64 rows x 32k f32 -> bf16, unit-major planes
      const float* sp = &src[(m0 + arow) * NPIX + k0 + au * 8];
      float4 v0 = *(const float4*)sp, v1 = *(const float4*)(sp + 4);
      float f[8] = {v0.x, v0.y, v0.z, v0.w, v1.x, v1.y, v1.z, v1.w};
      if (use_mask) {
        const float* mp = &maskf[k0 + au * 8];
        float4 q0 = *(const float4*)mp, q1 = *(const float4*)(mp + 4);
        f[0] *= q0.x; f[1] *= q0.y; f[2] *= q0.z; f[3] *= q0.w;
        f[4] *= q1.x; f[5] *= q1.y; f[6] *= q1.z; f[7] *= q1.w;
      }
      union { u16 u[8]; uint4 q; } pk;
#pragma unroll
      for (int j = 0; j < 8; ++j) pk.u[j] = f2bf(f[j]);
      *(uint4*)&Apl[(au * 64 + arow) * 8] = pk.q;
    }
    { // B: [32k x 64n] f32 -> transposed bf16 B_T[n][k], k-pairs packed as b32
      const float* r0 = &w1[(k0 + bp * 2) * HID + n0 + bf4 * 4];
      float4 v0 = *(const float4*)r0;
      float4 v1 = *(const float4*)(r0 + HID);
      u32 wp[4];
      wp[0] = (u32)f2bf(v0.x) | ((u32)f2bf(v1.x) << 16);
      wp[1] = (u32)f2bf(v0.y) | ((u32)f2bf(v1.y) << 16);
      wp[2] = (u32)f2bf(v0.z) | ((u32)f2bf(v1.z) << 16);
      wp[3] = (u32)f2bf(v0.w) | ((u32)f2bf(v1.w) << 16);
#pragma unroll
      for (int i = 0; i < 4; ++i)
        *(u32*)&Bt[(bf4 * 4 + i) * 40 + bp * 2] = wp[i];
    }
    __syncthreads();
    // wave wv owns m-frag wv (rows m0+wv*16..+15)
    const short8 a =
        *(const short8*)&Apl[((lane >> 4) * 64 + wv * 16 + (lane & 15)) * 8];
#pragma unroll
    for (int nf = 0; nf < 4; ++nf) {
      const short8 b =
          *(const short8*)&Bt[(nf * 16 + (lane & 15)) * 40 + (lane >> 4) * 8];
      acc[nf] = __builtin_amdgcn_mfma_f32_16x16x32_bf16(a, b, acc[nf], 0, 0, 0);
    }
  }
  // C/D: col=lane&15, row=(lane>>4)*4+reg (m89-verified)
  const int rbase = m0 + wv * 16 + ((lane >> 4) << 2);
  const int cl = lane & 15;
#pragma unroll
  for (int nf = 0; nf < 4; ++nf)
#pragma unroll
    for (int r = 0; r < 4; ++r)
      atomicAdd(&hpre[(rbase + r) * HID + n0 + nf * 16 + cl], acc[nf][r]);
}

// -------------------------------------------------------------- hbias ------
__global__ __launch_bounds__(256) void k_hbias(const float* __restrict__ hpre,
                                               const float* __restrict__ b1,
                                               u16* __restrict__ hbf) {
  const int i = blockIdx.x * 256 + threadIdx.x;   // grid 1024 -> 262144
  const float v = hpre[i] + b1[i & (HID - 1)];
  hbf[i] = f2bf(fmaxf(v, 0.f));
}

// ------------------------------------------------------ spline (RQS) -------
__device__ __forceinline__ void rqs_eval(const float* op, float x, float& y,
                                         float& ld) {
  float w[8], h[8], dv[8];
#pragma unroll
  for (int i = 0; i < 8; ++i) w[i] = op[i];
#pragma unroll
  for (int i = 0; i < 8; ++i) h[i] = op[8 + i];
#pragma unroll
  for (int i = 0; i < 8; ++i) dv[i] = op[16 + i];
  float mw = w[0], mh = h[0];
#pragma unroll
  for (int i = 1; i < 8; ++i) { mw = fmaxf(mw, w[i]); mh = fmaxf(mh, h[i]); }
  float sw = 0.f, sh = 0.f;
#pragma unroll
  for (int i = 0; i < 8; ++i) { w[i] = expf(w[i] - mw); sw += w[i]; }
#pragma unroll
  for (int i = 0; i < 8; ++i) { h[i] = expf(h[i] - mh); sh += h[i]; }
  const float rw = 16.f / sw, rh = 16.f / sh;   // 2*B * softmax
#pragma unroll
  for (int i = 0; i < 8; ++i) { w[i] *= rw; h[i] *= rh; }
#pragma unroll
  for (int i = 0; i < 8; ++i) {
    const float v = dv[i];
    dv[i] = (v > 20.f) ? v : log1pf(expf(v));   // softplus
  }
  const bool inside = (x >= -TB) && (x <= TB);
  const float xs = fminf(fmaxf(x, -TB), TB);
  int cnt = 0;
  float c = -TB;
#pragma unroll
  for (int i = 0; i < 8; ++i) { if (xs >= c) ++cnt; c += w[i]; }
  int idx = cnt - 1;
  idx = idx < 0 ? 0 : (idx > 7 ? 7 : idx);
  // select via unrolled constant-index compares (no dynamic reg indexing)
  float xk = -TB, yk = -TB, wk = w[0], hk = h[0], dk = dv[0], dk1 = 1.f;
#pragma unroll
  for (int i = 0; i < 8; ++i) {
    if (i < idx) { xk += w[i]; yk += h[i]; }
    wk = (i == idx) ? w[i] : wk;
    hk = (i == idx) ? h[i] : hk;
    dk = (i == idx) ? dv[i] : dk;
    dk1 = (i == (idx + 1)) ? dv[i] : dk1;   // idx==7 -> stays 1.0
  }
  const float sk = hk / wk;
  const float t = (xs - xk) / wk;
  const float tt = t * (1.f - t);
  const float den = sk + (dk1 + dk - 2.f * sk) * tt;
  const float omt = 1.f - t;
  y = yk + hk * (sk * t * t + dk * tt) / den;
  ld = logf(sk * sk * (dk1 * t * t + 2.f * sk * tt + dk * omt * omt)) -
       2.f * logf(den);
  if (!inside) { y = x; ld = 0.f; }
}

// ------------------------------------------------- gemm2 + fused spline ----
// o[:, col0:col0+48] = h @ w2 + b2, then RQS on the block's 2 pixels.
// M=256 (full batch, so w2 is streamed exactly once per pass), Ntile=48, Kc=32.
__global__ __launch_bounds__(256) void k_gemm2(
    const u16* __restrict__ hbf, const float* __restrict__ w2,
    const float* __restrict__ b2, const float* __restrict__ z,
    const float* __restrict__ maskf, float* __restrict__ zout2,
    float* __restrict__ outz, float* __restrict__ ldacc, const int pass2) {
  __shared__ __align__(16) union {
    struct { u16 Apl[4 * 256 * 8]; u16 Bt[48 * 40]; } st;  // 16384B + 3840B
    float o[256 * 49];                                     // 50176B (pad 49)
  } sm;

  const int tid = threadIdx.x;
  const int lane = tid & 63;
  const int wv = tid >> 6;
  const int col0 = blockIdx.x * 48;

  f32x4 acc[4][3];
#pragma unroll
  for (int i = 0; i < 4; ++i)
#pragma unroll
    for (int j = 0; j < 3; ++j) acc[i][j] = f32x4{0.f, 0.f, 0.f, 0.f};

  float b2v[3];
#pragma unroll
  for (int nf = 0; nf < 3; ++nf) b2v[nf] = b2[col0 + nf * 16 + (lane & 15)];

  const int bp = tid / 12;          // valid for tid<192: k-pair 0..15
  const int bf4 = tid - bp * 12;    // float4 col 0..11

  for (int kc = 0; kc < 32; ++kc) {
    const int k0 = kc * 32;
    __syncthreads();
    // A: global_load_lds, unit-major planes [u][256r][8]; wave wv does its 64 rows.
    // Per-lane gptr carries the layout permutation; LDS dest stays linear.
#pragma unroll
    for (int u = 0; u < 4; ++u) {
      const u16* gp = &hbf[(wv * 64 + lane) * HID + k0 + u * 8];
      glds16(gp, &sm.st.Apl[(u * 256 + wv * 64) * 8]);
    }
    // B: [32k x 48n] f32 -> transposed bf16 B_T[n][40k-pad]
    if (tid < 192) {
      const float* r0 = &w2[(k0 + bp * 2) * NC + col0 + bf4 * 4];
      float4 v0 = *(const float4*)r0;
      float4 v1 = *(const float4*)(r0 + NC);
      u32 wp[4];
      wp[0] = (u32)f2bf(v0.x) | ((u32)f2bf(v1.x) << 16);
      wp[1] = (u32)f2bf(v0.y) | ((u32)f2bf(v1.y) << 16);
      wp[2] = (u32)f2bf(v0.z) | ((u32)f2bf(v1.z) << 16);
      wp[3] = (u32)f2bf(v0.w) | ((u32)f2bf(v1.w) << 16);
#pragma unroll
      for (int i = 0; i < 4; ++i)
        *(u32*)&sm.st.Bt[(bf4 * 4 + i) * 40 + bp * 2] = wp[i];
    }
    __syncthreads();
    short8 af[4];
#pragma unroll
    for (int mi = 0; mi < 4; ++mi)
      af[mi] = *(const short8*)&sm.st
                   .Apl[((lane >> 4) * 256 + wv * 64 + mi * 16 + (lane & 15)) * 8];
#pragma unroll
    for (int nf = 0; nf < 3; ++nf) {
      const short8 b =
          *(const short8*)&sm.st.Bt[(nf * 16 + (lane & 15)) * 40 + (lane >> 4) * 8];
#pragma unroll
      for (int mi = 0; mi < 4; ++mi)
        acc[mi][nf] =
            __builtin_amdgcn_mfma_f32_16x16x32_bf16(af[mi], b, acc[mi][nf], 0, 0, 0);
    }
  }
  __syncthreads();   // staging region is about to be reused as o-tile
#pragma unroll
  for (int mi = 0; mi < 4; ++mi) {
    const int rb = wv * 64 + mi * 16 + ((lane >> 4) << 2);
#pragma unroll
    for (int nf = 0; nf < 3; ++nf) {
      const int cc = nf * 16 + (lane & 15);
#pragma unroll
      for (int r = 0; r < 4; ++r)
        sm.o[(rb + r) * 49 + cc] = acc[mi][nf][r] + b2v[nf];
    }
  }
  __syncthreads();
  // spline: thread t = batch row t; 2 pixels per block
  float ldsum = 0.f;
#pragma unroll
  for (int pi = 0; pi < 2; ++pi) {
    const float* op = &sm.o[tid * 49 + pi * 24];
    const int pix = blockIdx.x * 2 + pi;
    const float zv = z[tid * NPIX + pix];
    const float mk = maskf[pix];
    const float x = pass2 ? (zv * mk) : (zv * (mk + 1.f));
    float y, ld;
    rqs_eval(op, x, y, ld);
    if (pass2)
      outz[tid * NPIX + pix] = y + zout2[tid * NPIX + pix];
    else
      zout2[tid * NPIX + pix] = y;
    ldsum += ld;
  }
  atomicAdd(&ldacc[tid * 64 + (blockIdx.x & 63)], ldsum);
}

// -------------------------------------------------------------- final ------
__global__ __launch_bounds__(256) void k_final(const float* __restrict__ ldacc,
                                               const float* __restrict__ ld0,
                                               float* __restrict__ outl) {
  const int b = threadIdx.x;   // 1 block x 256
  float s = ld0[b];
#pragma unroll 8
  for (int j = 0; j < 64; ++j) s += ldacc[b * 64 + j];
  outl[b] = s;
}

// ------------------------------------------------------------- launch ------
extern "C" void kernel_launch(void* const* d_in, const int* in_sizes, int n_in,
                              void* d_out, int out_size, void* d_ws,
                              size_t ws_size, hipStream_t stream) {
  const float* z = (const float*)d_in[0];
  const float* ld0 = (const float*)d_in[1];
  const float* w1 = (const float*)d_in[2];
  const float* b1 = (const float*)d_in[3];
  const float* w2 = (const float*)d_in[4];
  const float* b2 = (const float*)d_in[5];
  const int* mask = (const int*)d_in[6];
  float* out = (float*)d_out;

  char* ws = (char*)d_ws;
  float* hpre = (float*)ws;                                    // 2 MB
  u16* hbf = (u16*)(ws + (2u << 20));                          // 512 KB
  float* zout2 = (float*)(ws + (2u << 20) + (1u << 19));       // 4 MB
  float* ldacc = (float*)(ws + (6u << 20) + (1u << 19));       // 64 KB
  float* maskf = (float*)(ws + (6u << 20) + (1u << 19) + (1u << 16)); // 16 KB
  const size_t need = (6u << 20) + (1u << 19) + (1u << 16) + (1u << 14);
  if (ws_size < need) return;

  float* hpre1 = hpre;
  float* hpre2 = hpre + BT * HID;

  k_prep<<<2048, 256, 0, stream>>>(hpre, ldacc, maskf, mask);
  // pass 1: params from net(z*m), transform z*(m+1)
  k_gemm1<<<dim3(16, 4, 8), 256, 0, stream>>>(z, maskf, w1, hpre1, 1);
  k_hbias<<<1024, 256, 0, stream>>>(hpre1, b1, hbf);
  k_gemm2<<<2048, 256, 0, stream>>>(hbf, w2, b2, z, maskf, zout2, nullptr,
                                    ldacc, 0);
  // pass 2: params from net(z_out2), transform z*m; out = z_in2 + z_out2
  k_gemm1<<<dim3(16, 4, 8), 256, 0, stream>>>(zout2, maskf, w1, hpre2, 0);
  k_hbias<<<1024, 256, 0, stream>>>(hpre2, b1, hbf);
  k_gemm2<<<2048, 256, 0, stream>>>(hbf, w2, b2, z, maskf, zout2, out, ldacc, 1);
  k_final<<<1, 256, 0, stream>>>(ldacc, ld0, out + BT * NPIX);
}

// Round 2
// 857.785 us; speedup vs baseline: 1.2591x; 1.2591x over previous
//
#include <hip/hip_runtime.h>
#include <hip/hip_bf16.h>
#include <stdint.h>

typedef unsigned short u16;
typedef unsigned int u32;

#define BT 256
#define NPIX 4096
#define HID 1024
#define NC 98304          // NPIX*3*K_BINS
#define TB 8.0f

typedef __attribute__((ext_vector_type(8))) short short8;   // 8 bf16 (4 VGPR)
typedef __attribute__((ext_vector_type(4))) float f32x4;

typedef __attribute__((address_space(1))) void as1_void;
typedef __attribute__((address_space(3))) void as3_void;

__device__ __forceinline__ u16 f2bf(float f) {
  union { __hip_bfloat16 b; u16 u; } cv;
  cv.b = __float2bfloat16(f);   // RNE
  return cv.u;
}

__device__ __forceinline__ void glds16(const void* g, void* l) {
  // width=16 direct global->LDS; LDS dest wave-uniform base + lane*16
  __builtin_amdgcn_global_load_lds((as1_void*)g, (as3_void*)l, 16, 0, 0);
}

__device__ __forceinline__ void vmw0() { asm volatile("s_waitcnt vmcnt(0)" ::: "memory"); }
__device__ __forceinline__ void vmw4() { asm volatile("s_waitcnt vmcnt(4)" ::: "memory"); }
__device__ __forceinline__ void vmw5() { asm volatile("s_waitcnt vmcnt(5)" ::: "memory"); }
__device__ __forceinline__ void lgkm0() { asm volatile("s_waitcnt lgkmcnt(0)" ::: "memory"); }
__device__ __forceinline__ void sched0() { __builtin_amdgcn_sched_barrier(0); }

// ---------------------------------------------------------------- prep ------
__global__ __launch_bounds__(256) void k_prep(float* hpre, float* ldacc) {
  const int i = blockIdx.x * 256 + threadIdx.x;   // grid 2048 -> 524288 exactly
  hpre[i] = 0.f;
  if (i < BT * 64) ldacc[i] = 0.f;
}

// ---------------------------------------------------------------- pack ------
// w2 [1024][98304] f32 -> w2b bf16 tiles: tile(ct,kc) = [n=0..47][k=0..31],
// 3072 B each, row n = 64 B = 4 units of 16 B stored at unit' = u ^ ((n>>1)&3)
// (pre-swizzled so LDS ds_read_b128 B-frag reads are bank-conflict-free).
__global__ __launch_bounds__(256) void k_pack(const float* __restrict__ w2,
                                              u16* __restrict__ w2b) {
  const int T = blockIdx.x * 256 + threadIdx.x;   // 3,145,728 threads
  const int n = T % 48;
  const int r = T / 48;          // 65536 = ct*32 + kc
  const int kc = r & 31;
  const int ct = r >> 5;
  const float* sp = w2 + (size_t)(kc * 32) * NC + ct * 48 + n;
  u16* dp = w2b + (size_t)(ct * 32 + kc) * 1536 + n * 32;
  float f[32];
#pragma unroll
  for (int k = 0; k < 32; ++k) f[k] = sp[(size_t)k * NC];
#pragma unroll
  for (int u = 0; u < 4; ++u) {
    union { u16 h[8]; uint4 q; } pk;
#pragma unroll
    for (int j = 0; j < 8; ++j) pk.h[j] = f2bf(f[u * 8 + j]);
    *(uint4*)&dp[(u ^ ((n >> 1) & 3)) * 8] = pk.q;
  }
}

// -------------------------------------------------------------- gemm1 ------
// h_pre += (x[*mask]) @ w1 ; split-K=16, f32 atomics. Reg-prefetch dbuf,
// raw barrier with lgkmcnt-only drain (loads stay in flight).
__global__ __launch_bounds__(256) void k_gemm1(
    const float* __restrict__ src, const float* __restrict__ w1,
    float* __restrict__ hpre, const int use_mask) {
  __shared__ __align__(16) u16 Apl[2][2048];   // [buf][(au*64+arow)*8]
  __shared__ __align__(16) u16 Bt[2][2560];    // [buf][n*40 + kpair*2]

  const int tid = threadIdx.x;
  const int lane = tid & 63;
  const int wv = tid >> 6;
  const int n0 = blockIdx.x * 64;
  const int m0 = blockIdx.y * 64;
  const int kbase = blockIdx.z * 256;

  f32x4 acc[4];
#pragma unroll
  for (int i = 0; i < 4; ++i) acc[i] = f32x4{0.f, 0.f, 0.f, 0.f};

  const int arow = tid >> 2, au = tid & 3;
  const int bp = tid >> 4, bf4 = tid & 15;

  float4 ra0, ra1, rb0, rb1;
#define G1_LOAD(KC)                                                        \
  {                                                                        \
    const int k0 = kbase + (KC) * 32;                                      \
    const float* sp = &src[(m0 + arow) * NPIX + k0 + au * 8];              \
    ra0 = *(const float4*)sp;                                              \
    ra1 = *(const float4*)(sp + 4);                                        \
    const float* rp = &w1[(k0 + bp * 2) * HID + n0 + bf4 * 4];             \
    rb0 = *(const float4*)rp;                                              \
    rb1 = *(const float4*)(rp + HID);                                      \
  }

  G1_LOAD(0);
  for (int t = 0; t < 8; ++t) {
    const int cur = t & 1;
    { // repack A (mask = k%2 checkerboard: zero even-k lanes)
      float f[8] = {ra0.x, ra0.y, ra0.z, ra0.w, ra1.x, ra1.y, ra1.z, ra1.w};
      if (use_mask) { f[0] = 0.f; f[2] = 0.f; f[4] = 0.f; f[6] = 0.f; }
      union { u16 u[8]; uint4 q; } pk;
#pragma unroll
      for (int j = 0; j < 8; ++j) pk.u[j] = f2bf(f[j]);
      *(uint4*)&Apl[cur][(au * 64 + arow) * 8] = pk.q;
    }
    { // repack B transposed, k-pairs packed
      u32 wp[4];
      wp[0] = (u32)f2bf(rb0.x) | ((u32)f2bf(rb1.x) << 16);
      wp[1] = (u32)f2bf(rb0.y) | ((u32)f2bf(rb1.y) << 16);
      wp[2] = (u32)f2bf(rb0.z) | ((u32)f2bf(rb1.z) << 16);
      wp[3] = (u32)f2bf(rb0.w) | ((u32)f2bf(rb1.w) << 16);
#pragma unroll
      for (int i = 0; i < 4; ++i)
        *(u32*)&Bt[cur][(bf4 * 4 + i) * 40 + bp * 2] = wp[i];
    }
    if (t < 7) G1_LOAD(t + 1);      // next chunk flies over barrier+MFMA
    lgkm0();
    sched0();
    __builtin_amdgcn_s_barrier();
    sched0();
    const short8 a =
        *(const short8*)&Apl[cur][((lane >> 4) * 64 + wv * 16 + (lane & 15)) * 8];
#pragma unroll
    for (int nf = 0; nf < 4; ++nf) {
      const short8 b =
          *(const short8*)&Bt[cur][(nf * 16 + (lane & 15)) * 40 + (lane >> 4) * 8];
      acc[nf] = __builtin_amdgcn_mfma_f32_16x16x32_bf16(a, b, acc[nf], 0, 0, 0);
    }
    lgkm0();   // reads of cur complete before next iter overwrites cur^1 path
    sched0();
    __builtin_amdgcn_s_barrier();
    sched0();
  }
  const int rbase = m0 + wv * 16 + ((lane >> 4) << 2);
  const int cl = lane & 15;
#pragma unroll
  for (int nf = 0; nf < 4; ++nf)
#pragma unroll
    for (int r = 0; r < 4; ++r)
      atomicAdd(&hpre[(rbase + r) * HID + n0 + nf * 16 + cl], acc[nf][r]);
#undef G1_LOAD
}

// -------------------------------------------------------------- hbias ------
// bias+relu+bf16, written in gemm2's A-plane layout: hbf2[kc][u][row][e]
__global__ __launch_bounds__(256) void k_hbias(const float* __restrict__ hpre,
                                               const float* __restrict__ b1,
                                               u16* __restrict__ hbf2) {
  const int i = blockIdx.x * 256 + threadIdx.x;   // grid 1024 -> 262144
  const int e = i & 7;
  const int row = (i >> 3) & 255;
  const int u = (i >> 11) & 3;
  const int kc = i >> 13;
  const int k = kc * 32 + u * 8 + e;
  const float v = hpre[row * HID + k] + b1[k];
  hbf2[i] = f2bf(fmaxf(v, 0.f));
}

// ------------------------------------------------------ spline (RQS) -------
__device__ __forceinline__ void rqs_eval(const float* op, float x, float& y,
                                         float& ld) {
  float w[8], h[8], dv[8];
#pragma unroll
  for (int i = 0; i < 8; ++i) w[i] = op[i];
#pragma unroll
  for (int i = 0; i < 8; ++i) h[i] = op[8 + i];
#pragma unroll
  for (int i = 0; i < 8; ++i) dv[i] = op[16 + i];
  float mw = w[0], mh = h[0];
#pragma unroll
  for (int i = 1; i < 8; ++i) { mw = fmaxf(mw, w[i]); mh = fmaxf(mh, h[i]); }
  float sw = 0.f, sh = 0.f;
#pragma unroll
  for (int i = 0; i < 8; ++i) { w[i] = expf(w[i] - mw); sw += w[i]; }
#pragma unroll
  for (int i = 0; i < 8; ++i) { h[i] = expf(h[i] - mh); sh += h[i]; }
  const float rw = 16.f / sw, rh = 16.f / sh;
#pragma unroll
  for (int i = 0; i < 8; ++i) { w[i] *= rw; h[i] *= rh; }
#pragma unroll
  for (int i = 0; i < 8; ++i) {
    const float v = dv[i];
    dv[i] = (v > 20.f) ? v : log1pf(expf(v));   // softplus
  }
  const bool inside = (x >= -TB) && (x <= TB);
  const float xs = fminf(fmaxf(x, -TB), TB);
  int cnt = 0;
  float c = -TB;
#pragma unroll
  for (int i = 0; i < 8; ++i) { if (xs >= c) ++cnt; c += w[i]; }
  int idx = cnt - 1;
  idx = idx < 0 ? 0 : (idx > 7 ? 7 : idx);
  float xk = -TB, yk = -TB, wk = w[0], hk = h[0], dk = dv[0], dk1 = 1.f;
#pragma unroll
  for (int i = 0; i < 8; ++i) {
    if (i < idx) { xk += w[i]; yk += h[i]; }
    wk = (i == idx) ? w[i] : wk;
    hk = (i == idx) ? h[i] : hk;
    dk = (i == idx) ? dv[i] : dk;
    dk1 = (i == (idx + 1)) ? dv[i] : dk1;
  }
  const float sk = hk / wk;
  const float t = (xs - xk) / wk;
  const float tt = t * (1.f - t);
  const float den = sk + (dk1 + dk - 2.f * sk) * tt;
  const float omt = 1.f - t;
  y = yk + hk * (sk * t * t + dk * tt) / den;
  ld = logf(sk * sk * (dk1 * t * t + 2.f * sk * tt + dk * omt * omt)) -
       2.f * logf(den);
  if (!inside) { y = x; ld = 0.f; }
}

// ------------------------------------------------- gemm2 + fused spline ----
// o[:, ct*48..+48) = h @ w2 + b2 then RQS on the block's 2 pixels.
// Pipelined: 2 LDS buffers, counted vmcnt (never 0 in steady state),
// raw s_barriers; A and B staged entirely via global_load_lds of prepacked bf16.
__global__ __launch_bounds__(256) void k_gemm2(
    const u16* __restrict__ hbf2, const u16* __restrict__ w2b,
    const float* __restrict__ b2, const float* __restrict__ z,
    float* __restrict__ zout2, float* __restrict__ outz,
    float* __restrict__ ldacc, const int pass2) {
  __shared__ __align__(16) union {
    struct { u16 A[2][8192]; u16 B[2][1536]; } s;   // 32768 + 6144 B
    float o[256 * 49];                              // 50176 B
  } sm;

  const int tid = threadIdx.x;
  const int lane = tid & 63;
  const int wv = tid >> 6;
  const int ct = blockIdx.x;
  const u16* w2t = w2b + (size_t)ct * 32 * 1536;

  f32x4 acc[4][3];
#pragma unroll
  for (int i = 0; i < 4; ++i)
#pragma unroll
    for (int j = 0; j < 3; ++j) acc[i][j] = f32x4{0.f, 0.f, 0.f, 0.f};

  // epilogue operands preloaded (retire before staging batches)
  float b2v[3];
#pragma unroll
  for (int nf = 0; nf < 3; ++nf) b2v[nf] = b2[ct * 48 + nf * 16 + (lane & 15)];
  float zv[2], zo[2];
#pragma unroll
  for (int pi = 0; pi < 2; ++pi) {
    const int pix = ct * 2 + pi;
    zv[pi] = z[tid * NPIX + pix];
    zo[pi] = zout2[tid * NPIX + pix];
  }

#define STAGE(BUF, KC)                                                        \
  {                                                                           \
    _Pragma("unroll") for (int u = 0; u < 4; ++u) {                           \
      const u16* ga = hbf2 + (KC) * 8192 + (u * 256 + wv * 64 + lane) * 8;    \
      glds16(ga, &sm.s.A[BUF][(u * 256 + wv * 64) * 8]);                      \
    }                                                                         \
    if (wv < 3) {                                                             \
      const u16* gb = w2t + (KC) * 1536 + wv * 512 + lane * 8;                \
      glds16(gb, &sm.s.B[BUF][wv * 512]);                                     \
    }                                                                         \
  }

  STAGE(0, 0);
  STAGE(1, 1);

  for (int t = 0; t < 32; ++t) {
    const int cur = t & 1;
    if (t < 31) {                 // allow next batch to stay in flight
      if (wv < 3) vmw5(); else vmw4();
    } else {
      vmw0();
    }
    sched0();
    __builtin_amdgcn_s_barrier();   // buf cur fully staged (all waves)
    sched0();
    short8 af[4], bfr[3];
#pragma unroll
    for (int mi = 0; mi < 4; ++mi)
      af[mi] = *(const short8*)&sm.s
                   .A[cur][((lane >> 4) * 256 + wv * 64 + mi * 16 + (lane & 15)) * 8];
#pragma unroll
    for (int nf = 0; nf < 3; ++nf) {
      const int n = nf * 16 + (lane & 15);
      bfr[nf] = *(const short8*)&sm.s
                    .B[cur][n * 32 + (((lane >> 4) ^ ((n >> 1) & 3)) * 8)];
    }
    lgkm0();                        // frags in regs
    sched0();
    __builtin_amdgcn_s_barrier();   // all waves done reading buf cur
    sched0();
    if (t < 30) STAGE(cur, t + 2);  // overwrite cur; flies over MFMA + next iter
#pragma unroll
    for (int nf = 0; nf < 3; ++nf)
#pragma unroll
      for (int mi = 0; mi < 4; ++mi)
        acc[mi][nf] = __builtin_amdgcn_mfma_f32_16x16x32_bf16(af[mi], bfr[nf],
                                                              acc[mi][nf], 0, 0, 0);
  }
#undef STAGE

  // ---- epilogue: o tile via LDS (union), then fused spline ----
#pragma unroll
  for (int mi = 0; mi < 4; ++mi) {
    const int rb = wv * 64 + mi * 16 + ((lane >> 4) << 2);
#pragma unroll
    for (int nf = 0; nf < 3; ++nf) {
      const int cc = nf * 16 + (lane & 15);
#pragma unroll
      for (int r = 0; r < 4; ++r)
        sm.o[(rb + r) * 49 + cc] = acc[mi][nf][r] + b2v[nf];
    }
  }
  __syncthreads();
  float ldsum = 0.f;
#pragma unroll
  for (int pi = 0; pi < 2; ++pi) {
    const float* op = &sm.o[tid * 49 + pi * 24];
    const int pix = ct * 2 + pi;
    const float mk = (float)(pix & 1);          // mask = arange%2 (checkerboard)
    const float x = pass2 ? (zv[pi] * mk) : (zv[pi] * (mk + 1.f));
    float y, ld;
    rqs_eval(op, x, y, ld);
    if (pass2)
      outz[tid * NPIX + pix] = y + zo[pi];
    else
      zout2[tid * NPIX + pix] = y;
    ldsum += ld;
  }
  atomicAdd(&ldacc[tid * 64 + (ct & 63)], ldsum);
}

// -------------------------------------------------------------- final ------
__global__ __launch_bounds__(256) void k_final(const float* __restrict__ ldacc,
                                               const float* __restrict__ ld0,
                                               float* __restrict__ outl) {
  const int b = threadIdx.x;   // 1 block x 256
  float s = ld0[b];
#pragma unroll 8
  for (int j = 0; j < 64; ++j) s += ldacc[b * 64 + j];
  outl[b] = s;
}

// ------------------------------------------------------------- launch ------
extern "C" void kernel_launch(void* const* d_in, const int* in_sizes, int n_in,
                              void* d_out, int out_size, void* d_ws,
                              size_t ws_size, hipStream_t stream) {
  const float* z = (const float*)d_in[0];
  const float* ld0 = (const float*)d_in[1];
  const float* w1 = (const float*)d_in[2];
  const float* b1 = (const float*)d_in[3];
  const float* w2 = (const float*)d_in[4];
  const float* b2 = (const float*)d_in[5];
  float* out = (float*)d_out;

  char* ws = (char*)d_ws;
  const size_t W2B = 201326592;                       // 2048*32*3072
  u16* w2b = (u16*)ws;
  float* hpre = (float*)(ws + W2B);                   // 2 MB (2 buffers)
  u16* hbf2 = (u16*)(ws + W2B + (2u << 20));          // 512 KB
  float* zout2 = (float*)(ws + W2B + (2u << 20) + (1u << 19));        // 4 MB
  float* ldacc = (float*)(ws + W2B + (6u << 20) + (1u << 19));        // 64 KB
  const size_t need = W2B + (6u << 20) + (1u << 19) + (1u << 16);
  if (ws_size < need) return;

  float* hpre1 = hpre;
  float* hpre2 = hpre + BT * HID;

  k_prep<<<2048, 256, 0, stream>>>(hpre, ldacc);
  k_pack<<<12288, 256, 0, stream>>>(w2, w2b);
  // pass 1: params from net(z*m), transform z*(m+1)
  k_gemm1<<<dim3(16, 4, 16), 256, 0, stream>>>(z, w1, hpre1, 1);
  k_hbias<<<1024, 256, 0, stream>>>(hpre1, b1, hbf2);
  k_gemm2<<<2048, 256, 0, stream>>>(hbf2, w2b, b2, z, zout2, nullptr, ldacc, 0);
  // pass 2: params from net(z_out2), transform z*m; out = z_in2 + z_out2
  k_gemm1<<<dim3(16, 4, 16), 256, 0, stream>>>(zout2, w1, hpre2, 0);
  k_hbias<<<1024, 256, 0, stream>>>(hpre2, b1, hbf2);
  k_gemm2<<<2048, 256, 0, stream>>>(hbf2, w2b, b2, z, zout2, out, ldacc, 1);
  k_final<<<1, 256, 0, stream>>>(ldacc, ld0, out + BT * NPIX);
}